// Round 14
// baseline (363.583 us; speedup 1.0000x reference)
//
#include <hip/hip_runtime.h>
#include <hip/hip_cooperative_groups.h>

namespace cg = cooperative_groups;

#define NN 100000            // nodes
#define NE 1200000           // edges
#define NRR 400000           // N*R segments
#define NBIN 98              // bins of 4096 segs: ceil(400000/4096)
#define CEPB 12245           // coop passA edges per block: ceil(NE/98)

typedef float f32x4 __attribute__((ext_vector_type(4)));
typedef __bf16 bf16x8 __attribute__((ext_vector_type(8)));

__device__ __forceinline__ float sigmoidf_(float x){ return 1.0f/(1.0f+__expf(-x)); }

// ---------------- cooperative front-end: hist+tobf16+prep | scan | passA | passB ----
// 98 blocks x 1024 threads, 3 grid syncs. Replaces 6 dispatches (memset, binhist,
// binscan, passA, passB, tobf16, prep) with 1: the r13 accounting shows ~105 us
// of the 299 is inter-dispatch overhead (~8 us x ~13 boundaries), so boundary
// count is the lever. Sort logic is verbatim from the r13 champion kernels.
__global__ __launch_bounds__(1024)
void sortprep_kernel(const int* __restrict__ src, const int* __restrict__ dst,
                     const int* __restrict__ rel,
                     const float* __restrict__ xf, __bf16* __restrict__ xb,
                     const float* __restrict__ w,  const float* __restrict__ b,
                     const float* __restrict__ ws, const float* __restrict__ bs,
                     const float* __restrict__ pw, const float* __restrict__ pb,
                     const float* __restrict__ tw, const float* __restrict__ tb,
                     const float* __restrict__ w2,  const float* __restrict__ b2,
                     const float* __restrict__ ws2, const float* __restrict__ bs2,
                     const float* __restrict__ pw2, const float* __restrict__ pb2,
                     const float* __restrict__ tw2, const float* __restrict__ tb2,
                     __bf16* __restrict__ W1a, __bf16* __restrict__ W2a,
                     float* __restrict__ B1a, float* __restrict__ B2a,
                     __bf16* __restrict__ W1b, __bf16* __restrict__ W2b,
                     float* __restrict__ B1b, float* __restrict__ B2b,
                     int* __restrict__ hpart,        // [NBIN][NBIN] partial hists
                     unsigned* __restrict__ ebin, int* __restrict__ bincur,
                     int* __restrict__ soff, unsigned* __restrict__ ebuck)
{
  cg::grid_group grid = cg::this_grid();
  __shared__ int st[4096];            // phase1/3: hist+runbase; phase4: seg counters
  __shared__ int aux[NBIN + 2];       // binoff (exclusive scan), aux[NBIN]=NE
  __shared__ int wsum[16], wbase[16];

  const int t   = threadIdx.x;
  const int bid = blockIdx.x;
  const int lo  = bid*CEPB, hi = min(lo + CEPB, NE);

  // ---- phase 1: per-block bin hist (partials, no global atomics/memset) ----
  if (t < 128) st[t] = 0;
  __syncthreads();
  for (int e = lo + t; e < hi; e += 1024)
    atomicAdd(&st[(dst[e]*4 + rel[e]) >> 12], 1);

  // tobf16 (grid-stride, independent of hist)
  for (int i = (bid*1024 + t)*8; i < NN*64; i += NBIN*1024*8){
    f32x4 a = *(const f32x4*)(xf + i);
    f32x4 c = *(const f32x4*)(xf + i + 4);
    bf16x8 r;
    r[0]=(__bf16)a[0]; r[1]=(__bf16)a[1]; r[2]=(__bf16)a[2]; r[3]=(__bf16)a[3];
    r[4]=(__bf16)c[0]; r[5]=(__bf16)c[1]; r[6]=(__bf16)c[2]; r[7]=(__bf16)c[3];
    *(bf16x8*)(xb + i) = r;
  }
  // fragment-swizzled weight prep (verbatim index math from r13 prep_kernel)
  {
    int i = bid*1024 + t;
    if (i < 64*320) {
      int e = i & 7, lane = (i >> 3) & 63, j = (i >> 9) & 3, kbi = i >> 11;
      int n = j*16 + (lane & 15);
      int k = kbi*32 + (lane >> 4)*8 + e;
      float va = (k < 256) ? w[n*256 + k]  : ws[n*64 + (k - 256)];
      float vb = (k < 256) ? w2[n*256 + k] : ws2[n*64 + (k - 256)];
      W1a[i] = (__bf16)va;
      W1b[i] = (__bf16)vb;
    }
    if (i < 128*128) {
      int e = i & 7, lane = (i >> 3) & 63, j = (i >> 9) & 7, kbi = i >> 12;
      int n = j*16 + (lane & 15);
      int k = kbi*32 + (lane >> 4)*8 + e;
      float va = (n < 64) ? pw[n*128 + k]  : tw[(n - 64)*128 + k];
      float vb = (n < 64) ? pw2[n*128 + k] : tw2[(n - 64)*128 + k];
      W2a[i] = (__bf16)va;
      W2b[i] = (__bf16)vb;
    }
    if (i < 64)  { B1a[i] = b[i] + bs[i];  B1b[i] = b2[i] + bs2[i]; }
    if (i < 128) { B2a[i] = (i < 64) ? pb[i] : tb[i-64];
                   B2b[i] = (i < 64) ? pb2[i] : tb2[i-64]; }
    if (i == 0) soff[NRR] = NE;     // sentinel
  }
  __syncthreads();
  if (t < NBIN) hpart[bid*NBIN + t] = st[t];

  grid.sync();

  // ---- phase 2: every block builds identical binoff; block bid seeds bincur[bid] ----
  if (t < NBIN) {
    int s = 0;
    for (int k = 0; k < NBIN; ++k) s += hpart[k*NBIN + t];
    st[t] = s;                          // bincnt
  }
  __syncthreads();
  if (t == 0) {
    int s = 0;
    for (int i = 0; i < NBIN; ++i){ aux[i] = s; s += st[i]; }
    aux[NBIN] = NE;
    bincur[bid] = aux[bid];
  }

  grid.sync();

  // ---- phase 3 (passA, verbatim): sort this block's stripe into bins ----
  // st[0..97] = running count, st[128..225] = runbase
  if (t < 128) { st[t] = 0; }
  __syncthreads();
  for (int e = lo + t; e < hi; e += 1024)
    atomicAdd(&st[(dst[e]*4 + rel[e]) >> 12], 1);
  __syncthreads();
  if (t < NBIN){
    st[128 + t] = st[t] ? atomicAdd(&bincur[t], st[t]) : 0;
    st[t] = 0;
  }
  __syncthreads();
  for (int e = lo + t; e < hi; e += 1024){
    int seg = dst[e]*4 + rel[e];
    int bin = seg >> 12;
    int p = st[128 + bin] + atomicAdd(&st[bin], 1);
    ebin[p] = (unsigned)src[e] | ((unsigned)(seg & 4095) << 17);
  }

  grid.sync();

  // ---- phase 4 (passB, verbatim): block bid = bin bid ----
  const int base = aux[bid], end = aux[bid + 1];
  #pragma unroll
  for (int i = 0; i < 4; ++i) st[t*4 + i] = 0;
  __syncthreads();
  for (int e = base + t; e < end; e += 1024)
    atomicAdd(&st[(ebin[e] >> 17) & 4095], 1);
  __syncthreads();
  int h0 = st[t*4], h1 = st[t*4+1], h2 = st[t*4+2], h3 = st[t*4+3];
  int lsum = h0 + h1 + h2 + h3;
  int lane = t & 63, wv = t >> 6;
  int inc = lsum;
  #pragma unroll
  for (int o = 1; o < 64; o <<= 1){ int u = __shfl_up(inc, o); if (lane >= o) inc += u; }
  if (lane == 63) wsum[wv] = inc;
  __syncthreads();
  if (t == 0){ int s = 0; for (int i = 0; i < 16; ++i){ wbase[i] = s; s += wsum[i]; } }
  __syncthreads();
  int ex = base + wbase[wv] + (inc - lsum);
  int s0 = ex, s1 = ex + h0, s2 = s1 + h1, s3 = s2 + h2;
  st[t*4] = s0; st[t*4+1] = s1; st[t*4+2] = s2; st[t*4+3] = s3;
  int sg = bid*4096 + t*4;
  if (sg   < NRR) soff[sg]   = s0;
  if (sg+1 < NRR) soff[sg+1] = s1;
  if (sg+2 < NRR) soff[sg+2] = s2;
  if (sg+3 < NRR) soff[sg+3] = s3;
  __syncthreads();
  for (int e = base + t; e < end; e += 1024){
    unsigned u = ebin[e];
    int p = atomicAdd(&st[(u >> 17) & 4095], 1);
    ebuck[p] = u & 0x1FFFFu;
  }
}

// ---------------- gather-mean -> fragment-swizzled segb (r13 champion, verbatim) ----
__global__ __launch_bounds__(256)
void gather_kernel(const unsigned* __restrict__ ebuck, const int* __restrict__ soff,
                   const __bf16* __restrict__ inb, __bf16* __restrict__ segb){
  const int sgg = blockIdx.x*32 + (threadIdx.x >> 3);   // global segment id
  const int fl  = threadIdx.x & 7;                      // feature octet
  const int e0 = soff[sgg];
  const int e1 = soff[sgg + 1];        // sgg+1 <= NRR; soff[NRR]=NE sentinel
  const int c  = e1 - e0;

  f32x4 a0 = {0.f,0.f,0.f,0.f}, a1 = {0.f,0.f,0.f,0.f};
  f32x4 b0 = {0.f,0.f,0.f,0.f}, b1 = {0.f,0.f,0.f,0.f};
  int i = 0;
  for (; i + 2 <= c; i += 2){
    int s0 = (int)ebuck[e0 + i];
    int s1 = (int)ebuck[e0 + i + 1];
    bf16x8 v0 = *(const bf16x8*)(&inb[(size_t)s0*64 + fl*8]);
    bf16x8 v1 = *(const bf16x8*)(&inb[(size_t)s1*64 + fl*8]);
    a0[0]+=(float)v0[0]; a0[1]+=(float)v0[1]; a0[2]+=(float)v0[2]; a0[3]+=(float)v0[3];
    a1[0]+=(float)v0[4]; a1[1]+=(float)v0[5]; a1[2]+=(float)v0[6]; a1[3]+=(float)v0[7];
    b0[0]+=(float)v1[0]; b0[1]+=(float)v1[1]; b0[2]+=(float)v1[2]; b0[3]+=(float)v1[3];
    b1[0]+=(float)v1[4]; b1[1]+=(float)v1[5]; b1[2]+=(float)v1[6]; b1[3]+=(float)v1[7];
  }
  if (i < c){
    int s0 = (int)ebuck[e0 + i];
    bf16x8 v0 = *(const bf16x8*)(&inb[(size_t)s0*64 + fl*8]);
    a0[0]+=(float)v0[0]; a0[1]+=(float)v0[1]; a0[2]+=(float)v0[2]; a0[3]+=(float)v0[3];
    a1[0]+=(float)v0[4]; a1[1]+=(float)v0[5]; a1[2]+=(float)v0[6]; a1[3]+=(float)v0[7];
  }
  float inv = 1.0f / fmaxf((float)c, 1.0f);
  bf16x8 r;
  r[0]=(__bf16)((a0[0]+b0[0])*inv); r[1]=(__bf16)((a0[1]+b0[1])*inv);
  r[2]=(__bf16)((a0[2]+b0[2])*inv); r[3]=(__bf16)((a0[3]+b0[3])*inv);
  r[4]=(__bf16)((a1[0]+b1[0])*inv); r[5]=(__bf16)((a1[1]+b1[1])*inv);
  r[6]=(__bf16)((a1[2]+b1[2])*inv); r[7]=(__bf16)((a1[3]+b1[3])*inv);

  const int n   = sgg >> 2, rr = sgg & 3;   // node, relation
  const int nb  = n >> 4,  ml = n & 15;     // 16-node tile, row-in-tile
  const int kbi = rr*2 + (fl >> 2);
  const int kgs = fl & 3;
  *(bf16x8*)(&segb[(size_t)((nb*8 + kbi)*64 + kgs*16 + ml)*8]) = r;  // empty segs write 0
}

// ---------------- dense + highway (r13 champion, verbatim) ----
#define HSP 72    // LDS pitch (bf16) for h staging

template<bool LAYER1>
__global__ __launch_bounds__(256, 4)
void dense_kernel(const __bf16* __restrict__ segbs, // fragment-swizzled gather means
                  const __bf16* __restrict__ xinb,  // [N,64] conv self input
                  const __bf16* __restrict__ prevb, // [N,64] highway prev
                  const __bf16* __restrict__ W1s,   // swizzled [10][4][64][8]
                  const __bf16* __restrict__ W2s,   // swizzled [4][8][64][8]
                  const float* __restrict__ bias1,  // [64]
                  const float* __restrict__ bias2,  // [128]
                  __bf16* __restrict__ hb,          // layer1: conv out (bf16)
                  __bf16* __restrict__ gb,          // layer1: highway out (bf16)
                  float* __restrict__ outp)         // layer2: final fp32
{
  __shared__ __align__(16) __bf16 hs[64*HSP];
  __shared__ __align__(16) float outs[64*64];   // layer-2 fp32 store staging

  const int tid  = threadIdx.x;
  const int lane = tid & 63;
  const int wv   = tid >> 6;
  const int mloc = lane & 15;   // A-row / B-col within 16-tile
  const int kg   = lane >> 4;   // k-group
  const int wb   = blockIdx.x*64 + wv*16;   // wave's first output row (16-aligned)
  const int arow = min(wb + mloc, NN-1);    // A-operand row for scattered loads
  const int nbq  = min(wb, NN-16) >> 4;     // clamped node-tile (garbage ok, stores guarded)
  const size_t abase = (size_t)nbq * (8*512);

  f32x4 acc1[4] = {};

  // GEMM1 part 1: K = 0..256 from swizzled segb (coalesced A and B)
  #pragma unroll
  for (int kbi = 0; kbi < 8; ++kbi) {
    bf16x8 af = *(const bf16x8*)(&segbs[abase + (size_t)(kbi*64 + lane)*8]);
    #pragma unroll
    for (int j = 0; j < 4; ++j) {
      bf16x8 bf = *(const bf16x8*)(&W1s[((kbi*4 + j)*64 + lane)*8]);
      acc1[j] = __builtin_amdgcn_mfma_f32_16x16x32_bf16(af, bf, acc1[j], 0,0,0);
    }
  }
  // GEMM1 part 2: K = 256..320 from xinb (self loop; A scattered, B coalesced)
  #pragma unroll
  for (int kb = 0; kb < 64; kb += 32) {
    bf16x8 af = *(const bf16x8*)(&xinb[(size_t)arow*64 + kb + kg*8]);
    const int kbi = 8 + (kb >> 5);
    #pragma unroll
    for (int j = 0; j < 4; ++j) {
      bf16x8 bf = *(const bf16x8*)(&W1s[((kbi*4 + j)*64 + lane)*8]);
      acc1[j] = __builtin_amdgcn_mfma_f32_16x16x32_bf16(af, bf, acc1[j], 0,0,0);
    }
  }

  // epilogue 1: h = sigmoid(acc + bias1); stage bf16 in LDS (wave-private rows)
  #pragma unroll
  for (int j = 0; j < 4; ++j) {
    int col = j*16 + mloc;
    float b1 = bias1[col];
    #pragma unroll
    for (int r = 0; r < 4; ++r) {
      float hv = sigmoidf_(acc1[j][r] + b1);
      acc1[j][r] = hv;
      hs[(wv*16 + kg*4 + r)*HSP + col] = (__bf16)hv;
    }
  }

  // cooperative vectorized hb store (layer1) from the staged tile
  if (LAYER1) {
    #pragma unroll
    for (int i = 0; i < 2; ++i) {
      int r2 = i*8 + (lane >> 3);
      int c2 = lane & 7;
      bf16x8 v = *(const bf16x8*)(&hs[(wv*16 + r2)*HSP + c2*8]);
      int grow = wb + r2;
      if (grow < NN) *(bf16x8*)(&hb[(size_t)grow*64 + c2*8]) = v;
    }
  }

  f32x4 acc2[8] = {};
  // GEMM2 part 1: K = 0..64 -> c = h (A from LDS, B coalesced)
  #pragma unroll
  for (int kb = 0; kb < 64; kb += 32) {
    bf16x8 af = *(const bf16x8*)(&hs[(wv*16 + mloc)*HSP + kb + kg*8]);
    const int kbi = kb >> 5;
    #pragma unroll
    for (int j = 0; j < 8; ++j) {
      bf16x8 bf = *(const bf16x8*)(&W2s[((kbi*8 + j)*64 + lane)*8]);
      acc2[j] = __builtin_amdgcn_mfma_f32_16x16x32_bf16(af, bf, acc2[j], 0,0,0);
    }
  }
  // GEMM2 part 2: K = 64..128 -> c = prev (A scattered, B coalesced)
  #pragma unroll
  for (int kb = 0; kb < 64; kb += 32) {
    bf16x8 af = *(const bf16x8*)(&prevb[(size_t)arow*64 + kb + kg*8]);
    const int kbi = 2 + (kb >> 5);
    #pragma unroll
    for (int j = 0; j < 8; ++j) {
      bf16x8 bf = *(const bf16x8*)(&W2s[((kbi*8 + j)*64 + lane)*8]);
      acc2[j] = __builtin_amdgcn_mfma_f32_16x16x32_bf16(af, bf, acc2[j], 0,0,0);
    }
  }

  // epilogue 2: pr = relu(.+pb), g = sigmoid(.+tb), out = g*pr + (1-g)*h
  #pragma unroll
  for (int j = 0; j < 4; ++j) {
    int col = j*16 + mloc;
    float bp = bias2[col];
    float bt = bias2[64 + col];
    #pragma unroll
    for (int r = 0; r < 4; ++r) {
      float pr = fmaxf(acc2[j][r] + bp, 0.0f);
      float g  = sigmoidf_(acc2[j+4][r] + bt);
      float hv = acc1[j][r];
      float ov = g*pr + (1.0f - g)*hv;
      if (LAYER1) {
        hs[(wv*16 + kg*4 + r)*HSP + col] = (__bf16)ov;   // reuse hs (h consumed)
      } else {
        outs[(wv*16 + kg*4 + r)*64 + col] = ov;          // stage for coalesced store
      }
    }
  }
  if (LAYER1) {
    #pragma unroll
    for (int i = 0; i < 2; ++i) {
      int r2 = i*8 + (lane >> 3);
      int c2 = lane & 7;
      bf16x8 v = *(const bf16x8*)(&hs[(wv*16 + r2)*HSP + c2*8]);
      int grow = wb + r2;
      if (grow < NN) *(bf16x8*)(&gb[(size_t)grow*64 + c2*8]) = v;
    }
  } else {
    #pragma unroll
    for (int i = 0; i < 4; ++i) {
      int pos = i*256 + lane*4;     // 0..1023 over 16 rows x 64 f32
      int r2 = pos >> 6, c2 = pos & 63;
      int grow = wb + r2;
      if (grow < NN)
        *(f32x4*)(&outp[(size_t)grow*64 + c2]) =
            *(const f32x4*)(&outs[(wv*16 + r2)*64 + c2]);
    }
  }
}

extern "C" void kernel_launch(void* const* d_in, const int* in_sizes, int n_in,
                              void* d_out, int out_size, void* d_ws, size_t ws_size,
                              hipStream_t stream){
  const float* x    = (const float*)d_in[0];
  const int*   src  = (const int*)d_in[1];
  const int*   dst  = (const int*)d_in[2];
  const int*   rel  = (const int*)d_in[3];
  const float* c1w  = (const float*)d_in[4];
  const float* c1b  = (const float*)d_in[5];
  const float* c1ws = (const float*)d_in[6];
  const float* c1bs = (const float*)d_in[7];
  const float* h1pw = (const float*)d_in[8];
  const float* h1pb = (const float*)d_in[9];
  const float* h1tw = (const float*)d_in[10];
  const float* h1tb = (const float*)d_in[11];
  const float* c2w  = (const float*)d_in[12];
  const float* c2b  = (const float*)d_in[13];
  const float* c2ws = (const float*)d_in[14];
  const float* c2bs = (const float*)d_in[15];
  const float* h2pw = (const float*)d_in[16];
  const float* h2pb = (const float*)d_in[17];
  const float* h2tw = (const float*)d_in[18];
  const float* h2tb = (const float*)d_in[19];

  char* p = (char*)d_ws;
  __bf16* segb = (__bf16*)p;  p += (size_t)NRR*64*2;
  __bf16* xb   = (__bf16*)p;  p += (size_t)NN*64*2;
  __bf16* h1b  = (__bf16*)p;  p += (size_t)NN*64*2;
  __bf16* g1b  = (__bf16*)p;  p += (size_t)NN*64*2;
  unsigned* ebuck = (unsigned*)p; p += (size_t)NE*4;
  unsigned* ebin  = (unsigned*)p; p += (size_t)NE*4;
  int* soff    = (int*)p;     p += (size_t)(NRR+8)*4;
  int* hpart   = (int*)p;     p += (size_t)NBIN*NBIN*4;
  int* bincur  = (int*)p;     p += 128*4;
  __bf16* W1a  = (__bf16*)p;  p += 64*320*2;
  __bf16* W2a  = (__bf16*)p;  p += 128*128*2;
  __bf16* W1b  = (__bf16*)p;  p += 64*320*2;
  __bf16* W2b  = (__bf16*)p;  p += 128*128*2;
  float* B1a   = (float*)p;   p += 64*4;
  float* B2a   = (float*)p;   p += 128*4;
  float* B1b   = (float*)p;   p += 64*4;
  float* B2b   = (float*)p;   p += 128*4;

  float* out = (float*)d_out;

  // one cooperative dispatch replaces memset+binhist+binscan+passA+passB+tobf16+prep
  void* args[] = {
    (void*)&src, (void*)&dst, (void*)&rel,
    (void*)&x, (void*)&xb,
    (void*)&c1w, (void*)&c1b, (void*)&c1ws, (void*)&c1bs,
    (void*)&h1pw, (void*)&h1pb, (void*)&h1tw, (void*)&h1tb,
    (void*)&c2w, (void*)&c2b, (void*)&c2ws, (void*)&c2bs,
    (void*)&h2pw, (void*)&h2pb, (void*)&h2tw, (void*)&h2tb,
    (void*)&W1a, (void*)&W2a, (void*)&B1a, (void*)&B2a,
    (void*)&W1b, (void*)&W2b, (void*)&B1b, (void*)&B2b,
    (void*)&hpart, (void*)&ebin, (void*)&bincur, (void*)&soff, (void*)&ebuck
  };
  hipLaunchCooperativeKernel((void*)sortprep_kernel, dim3(NBIN), dim3(1024),
                             args, 0, stream);

  // layer 1
  gather_kernel<<<NRR/32, 256, 0, stream>>>(ebuck, soff, xb, segb);
  dense_kernel<true><<<(NN+63)/64, 256, 0, stream>>>(segb, xb, xb, W1a, W2a, B1a, B2a,
                                                     h1b, g1b, nullptr);
  // layer 2
  gather_kernel<<<NRR/32, 256, 0, stream>>>(ebuck, soff, g1b, segb);
  dense_kernel<false><<<(NN+63)/64, 256, 0, stream>>>(segb, g1b, h1b, W1b, W2b, B1b, B2b,
                                                      nullptr, nullptr, out);
}

// Round 15
// 297.791 us; speedup vs baseline: 1.2209x; 1.2209x over previous
//
#include <hip/hip_runtime.h>

#define NN 100000            // nodes
#define NE 1200000           // edges
#define NRR 400000           // N*R segments
#define NBIN 98              // bins of 4096 segs: ceil(400000/4096)
#define EPB 4096             // passA edges per block

typedef float f32x4 __attribute__((ext_vector_type(4)));
typedef __bf16 bf16x8 __attribute__((ext_vector_type(8)));

__device__ __forceinline__ float sigmoidf_(float x){ return 1.0f/(1.0f+__expf(-x)); }

// ---------------- bin histogram (98 bins of 4096 segs) ----------------
__global__ __launch_bounds__(256)
void binhist_kernel(const int* __restrict__ dst, const int* __restrict__ rel,
                    int* __restrict__ bincnt){
  __shared__ int h[NBIN];
  int t = threadIdx.x;
  if (t < NBIN) h[t] = 0;
  __syncthreads();
  for (int e = blockIdx.x*256 + t; e < NE; e += 512*256){
    int bin = (dst[e]*4 + rel[e]) >> 12;
    atomicAdd(&h[bin], 1);
  }
  __syncthreads();
  if (t < NBIN && h[t]) atomicAdd(&bincnt[t], h[t]);
}

// ---------------- tiny exclusive scan of 98 bins + sentinels ----------------
__global__ void binscan_kernel(const int* __restrict__ bincnt, int* __restrict__ binoff,
                               int* __restrict__ bincur, int* __restrict__ soff){
  if (threadIdx.x == 0){
    int s = 0;
    for (int i = 0; i < NBIN; ++i){ binoff[i] = s; bincur[i] = s; s += bincnt[i]; }
    binoff[NBIN] = NE;
    soff[NRR] = NE;
  }
}

// ---------------- pass A: sort edges into 98 bins ----------------
// ebin entry = src | (seg_in_bin << 17), seg_in_bin = seg & 4095 (12 bits).
__global__ __launch_bounds__(256)
void passA_kernel(const int* __restrict__ src, const int* __restrict__ dst,
                  const int* __restrict__ rel, int* __restrict__ bincur,
                  unsigned* __restrict__ ebin){
  __shared__ int h[NBIN], runbase[NBIN];
  int t = threadIdx.x;
  if (t < NBIN) h[t] = 0;
  __syncthreads();
  int lo = blockIdx.x*EPB, hi = min(lo + EPB, NE);
  for (int e = lo + t; e < hi; e += 256)
    atomicAdd(&h[(dst[e]*4 + rel[e]) >> 12], 1);
  __syncthreads();
  if (t < NBIN){
    runbase[t] = h[t] ? atomicAdd(&bincur[t], h[t]) : 0;
    h[t] = 0;
  }
  __syncthreads();
  for (int e = lo + t; e < hi; e += 256){
    int seg = dst[e]*4 + rel[e];
    int bin = seg >> 12;
    int p = runbase[bin] + atomicAdd(&h[bin], 1);
    ebin[p] = (unsigned)src[e] | ((unsigned)(seg & 4095) << 17);
  }
}

// ---------------- pass B: per-bin segment-level counting sort ----------------
// Bin-local 48KB scatter window = L2-resident (the locality the r8 direct
// global scatter lacked: that hit 13x write amplification, WRITE_SIZE 83 MB).
__global__ __launch_bounds__(1024)
void passB_kernel(const unsigned* __restrict__ ebin, const int* __restrict__ binoff,
                  int* __restrict__ soff, unsigned* __restrict__ ebuck){
  __shared__ int st[4096];          // hist -> absolute starts -> cursors
  __shared__ int wsum[16], wbase[16];
  const int bin = blockIdx.x;
  const int t = threadIdx.x;
  const int base = binoff[bin], end = binoff[bin+1];
  #pragma unroll
  for (int i = 0; i < 4; ++i) st[t*4 + i] = 0;
  __syncthreads();
  for (int e = base + t; e < end; e += 1024)
    atomicAdd(&st[(ebin[e] >> 17) & 4095], 1);
  __syncthreads();
  int h0 = st[t*4], h1 = st[t*4+1], h2 = st[t*4+2], h3 = st[t*4+3];
  int lsum = h0 + h1 + h2 + h3;
  int lane = t & 63, wv = t >> 6;
  int inc = lsum;
  #pragma unroll
  for (int o = 1; o < 64; o <<= 1){ int u = __shfl_up(inc, o); if (lane >= o) inc += u; }
  if (lane == 63) wsum[wv] = inc;
  __syncthreads();
  if (t == 0){ int s = 0; for (int i = 0; i < 16; ++i){ wbase[i] = s; s += wsum[i]; } }
  __syncthreads();
  int ex = base + wbase[wv] + (inc - lsum);
  int s0 = ex, s1 = ex + h0, s2 = s1 + h1, s3 = s2 + h2;
  st[t*4] = s0; st[t*4+1] = s1; st[t*4+2] = s2; st[t*4+3] = s3;
  int sg = bin*4096 + t*4;
  if (sg   < NRR) soff[sg]   = s0;
  if (sg+1 < NRR) soff[sg+1] = s1;
  if (sg+2 < NRR) soff[sg+2] = s2;
  if (sg+3 < NRR) soff[sg+3] = s3;
  __syncthreads();
  for (int e = base + t; e < end; e += 1024){
    unsigned u = ebin[e];
    int p = atomicAdd(&st[(u >> 17) & 4095], 1);
    ebuck[p] = u & 0x1FFFFu;
  }
}

// ---------------- conversions / weight prep ----------------
__global__ void tobf16_kernel(const float* __restrict__ xf, __bf16* __restrict__ xb){
  int i = (blockIdx.x*256 + threadIdx.x)*8;
  if (i < NN*64){
    f32x4 a = *(const f32x4*)(xf + i);
    f32x4 b = *(const f32x4*)(xf + i + 4);
    bf16x8 r;
    r[0]=(__bf16)a[0]; r[1]=(__bf16)a[1]; r[2]=(__bf16)a[2]; r[3]=(__bf16)a[3];
    r[4]=(__bf16)b[0]; r[5]=(__bf16)b[1]; r[6]=(__bf16)b[2]; r[7]=(__bf16)b[3];
    *(bf16x8*)(xb + i) = r;
  }
}

// Fragment-swizzled weights (both layers in one launch):
// B-fragment for lane (mloc=lane&15, kg=lane>>4) of output-tile j, k-tile kbi
// is stored at ((kbi*J + j)*64 + lane)*8 -> dense B-loads fully coalesced.
// W1s: J=4, kbi 0..9 (K=320: 0..255 upd, 256..319 self). W2s: J=8, kbi 0..3.
__global__ void prep_kernel(const float* __restrict__ w,  const float* __restrict__ b,
                            const float* __restrict__ ws, const float* __restrict__ bs,
                            const float* __restrict__ pw, const float* __restrict__ pb,
                            const float* __restrict__ tw, const float* __restrict__ tb,
                            const float* __restrict__ w2,  const float* __restrict__ b2,
                            const float* __restrict__ ws2, const float* __restrict__ bs2,
                            const float* __restrict__ pw2, const float* __restrict__ pb2,
                            const float* __restrict__ tw2, const float* __restrict__ tb2,
                            __bf16* __restrict__ W1a, __bf16* __restrict__ W2a,
                            float* __restrict__ B1a, float* __restrict__ B2a,
                            __bf16* __restrict__ W1b, __bf16* __restrict__ W2b,
                            float* __restrict__ B1b, float* __restrict__ B2b){
  int i = blockIdx.x*256 + threadIdx.x;
  if (i < 64*320) {
    int e = i & 7, lane = (i >> 3) & 63, j = (i >> 9) & 3, kbi = i >> 11;
    int n = j*16 + (lane & 15);
    int k = kbi*32 + (lane >> 4)*8 + e;
    float va = (k < 256) ? w[n*256 + k]  : ws[n*64 + (k - 256)];
    float vb = (k < 256) ? w2[n*256 + k] : ws2[n*64 + (k - 256)];
    W1a[i] = (__bf16)va;
    W1b[i] = (__bf16)vb;
  }
  if (i < 128*128) {
    int e = i & 7, lane = (i >> 3) & 63, j = (i >> 9) & 7, kbi = i >> 12;
    int n = j*16 + (lane & 15);
    int k = kbi*32 + (lane >> 4)*8 + e;
    float va = (n < 64) ? pw[n*128 + k]  : tw[(n - 64)*128 + k];
    float vb = (n < 64) ? pw2[n*128 + k] : tw2[(n - 64)*128 + k];
    W2a[i] = (__bf16)va;
    W2b[i] = (__bf16)vb;
  }
  if (i < 64)  { B1a[i] = b[i] + bs[i];  B1b[i] = b2[i] + bs2[i]; }
  if (i < 128) { B2a[i] = (i < 64) ? pb[i] : tb[i-64];
                 B2b[i] = (i < 64) ? pb2[i] : tb2[i-64]; }
}

// ---------------- gather-mean -> fragment-swizzled segb ----------------
// BARRIER-FREE, zero LDS -> ~8 blocks/CU of pure TLP (the property the r11
// fusion destroyed: gather at GEMM occupancy lost more than segb saved).
// soff (1.6 MB) and ebuck (4.8 MB) are L2-resident; 8-lane groups reading the
// same ebuck word is a HW broadcast. Each 8-lane group owns one segment.
// Output layout (A-operand fragments): node tile nb=n>>4, mloc=n&15; octet fl
// of relation r: kbi=2r+(fl>>2), kg=fl&3 -> dense GEMM1 A-load coalesced.
__global__ __launch_bounds__(256)
void gather_kernel(const unsigned* __restrict__ ebuck, const int* __restrict__ soff,
                   const __bf16* __restrict__ inb, __bf16* __restrict__ segb){
  const int sgg = blockIdx.x*32 + (threadIdx.x >> 3);   // global segment id
  const int fl  = threadIdx.x & 7;                      // feature octet
  const int e0 = soff[sgg];
  const int e1 = soff[sgg + 1];        // sgg+1 <= NRR; soff[NRR]=NE sentinel
  const int c  = e1 - e0;

  f32x4 a0 = {0.f,0.f,0.f,0.f}, a1 = {0.f,0.f,0.f,0.f};
  f32x4 b0 = {0.f,0.f,0.f,0.f}, b1 = {0.f,0.f,0.f,0.f};
  int i = 0;
  for (; i + 2 <= c; i += 2){
    int s0 = (int)ebuck[e0 + i];
    int s1 = (int)ebuck[e0 + i + 1];
    bf16x8 v0 = *(const bf16x8*)(&inb[(size_t)s0*64 + fl*8]);
    bf16x8 v1 = *(const bf16x8*)(&inb[(size_t)s1*64 + fl*8]);
    a0[0]+=(float)v0[0]; a0[1]+=(float)v0[1]; a0[2]+=(float)v0[2]; a0[3]+=(float)v0[3];
    a1[0]+=(float)v0[4]; a1[1]+=(float)v0[5]; a1[2]+=(float)v0[6]; a1[3]+=(float)v0[7];
    b0[0]+=(float)v1[0]; b0[1]+=(float)v1[1]; b0[2]+=(float)v1[2]; b0[3]+=(float)v1[3];
    b1[0]+=(float)v1[4]; b1[1]+=(float)v1[5]; b1[2]+=(float)v1[6]; b1[3]+=(float)v1[7];
  }
  if (i < c){
    int s0 = (int)ebuck[e0 + i];
    bf16x8 v0 = *(const bf16x8*)(&inb[(size_t)s0*64 + fl*8]);
    a0[0]+=(float)v0[0]; a0[1]+=(float)v0[1]; a0[2]+=(float)v0[2]; a0[3]+=(float)v0[3];
    a1[0]+=(float)v0[4]; a1[1]+=(float)v0[5]; a1[2]+=(float)v0[6]; a1[3]+=(float)v0[7];
  }
  float inv = 1.0f / fmaxf((float)c, 1.0f);
  bf16x8 r;
  r[0]=(__bf16)((a0[0]+b0[0])*inv); r[1]=(__bf16)((a0[1]+b0[1])*inv);
  r[2]=(__bf16)((a0[2]+b0[2])*inv); r[3]=(__bf16)((a0[3]+b0[3])*inv);
  r[4]=(__bf16)((a1[0]+b1[0])*inv); r[5]=(__bf16)((a1[1]+b1[1])*inv);
  r[6]=(__bf16)((a1[2]+b1[2])*inv); r[7]=(__bf16)((a1[3]+b1[3])*inv);

  const int n   = sgg >> 2, rr = sgg & 3;   // node, relation
  const int nb  = n >> 4,  ml = n & 15;     // 16-node tile, row-in-tile
  const int kbi = rr*2 + (fl >> 2);
  const int kgs = fl & 3;
  *(bf16x8*)(&segb[(size_t)((nb*8 + kbi)*64 + kgs*16 + ml)*8]) = r;  // empty segs write 0
}

// ---------------- dense + highway (swizzled operands; r6/r7 champion) ----
#define HSP 72    // LDS pitch (bf16) for h staging

template<bool LAYER1>
__global__ __launch_bounds__(256, 4)
void dense_kernel(const __bf16* __restrict__ segbs, // fragment-swizzled gather means
                  const __bf16* __restrict__ xinb,  // [N,64] conv self input
                  const __bf16* __restrict__ prevb, // [N,64] highway prev
                  const __bf16* __restrict__ W1s,   // swizzled [10][4][64][8]
                  const __bf16* __restrict__ W2s,   // swizzled [4][8][64][8]
                  const float* __restrict__ bias1,  // [64]
                  const float* __restrict__ bias2,  // [128]
                  __bf16* __restrict__ hb,          // layer1: conv out (bf16)
                  __bf16* __restrict__ gb,          // layer1: highway out (bf16)
                  float* __restrict__ outp)         // layer2: final fp32
{
  __shared__ __align__(16) __bf16 hs[64*HSP];
  __shared__ __align__(16) float outs[64*64];   // layer-2 fp32 store staging

  const int tid  = threadIdx.x;
  const int lane = tid & 63;
  const int wv   = tid >> 6;
  const int mloc = lane & 15;   // A-row / B-col within 16-tile
  const int kg   = lane >> 4;   // k-group
  const int wb   = blockIdx.x*64 + wv*16;   // wave's first output row (16-aligned)
  const int arow = min(wb + mloc, NN-1);    // A-operand row for scattered loads
  const int nbq  = min(wb, NN-16) >> 4;     // clamped node-tile (garbage ok, stores guarded)
  const size_t abase = (size_t)nbq * (8*512);

  f32x4 acc1[4] = {};

  // GEMM1 part 1: K = 0..256 from swizzled segb (coalesced A and B)
  #pragma unroll
  for (int kbi = 0; kbi < 8; ++kbi) {
    bf16x8 af = *(const bf16x8*)(&segbs[abase + (size_t)(kbi*64 + lane)*8]);
    #pragma unroll
    for (int j = 0; j < 4; ++j) {
      bf16x8 bf = *(const bf16x8*)(&W1s[((kbi*4 + j)*64 + lane)*8]);
      acc1[j] = __builtin_amdgcn_mfma_f32_16x16x32_bf16(af, bf, acc1[j], 0,0,0);
    }
  }
  // GEMM1 part 2: K = 256..320 from xinb (self loop; A scattered, B coalesced)
  #pragma unroll
  for (int kb = 0; kb < 64; kb += 32) {
    bf16x8 af = *(const bf16x8*)(&xinb[(size_t)arow*64 + kb + kg*8]);
    const int kbi = 8 + (kb >> 5);
    #pragma unroll
    for (int j = 0; j < 4; ++j) {
      bf16x8 bf = *(const bf16x8*)(&W1s[((kbi*4 + j)*64 + lane)*8]);
      acc1[j] = __builtin_amdgcn_mfma_f32_16x16x32_bf16(af, bf, acc1[j], 0,0,0);
    }
  }

  // epilogue 1: h = sigmoid(acc + bias1); stage bf16 in LDS (wave-private rows)
  #pragma unroll
  for (int j = 0; j < 4; ++j) {
    int col = j*16 + mloc;
    float b1 = bias1[col];
    #pragma unroll
    for (int r = 0; r < 4; ++r) {
      float hv = sigmoidf_(acc1[j][r] + b1);
      acc1[j][r] = hv;
      hs[(wv*16 + kg*4 + r)*HSP + col] = (__bf16)hv;
    }
  }

  // cooperative vectorized hb store (layer1) from the staged tile
  if (LAYER1) {
    #pragma unroll
    for (int i = 0; i < 2; ++i) {
      int r2 = i*8 + (lane >> 3);
      int c2 = lane & 7;
      bf16x8 v = *(const bf16x8*)(&hs[(wv*16 + r2)*HSP + c2*8]);
      int grow = wb + r2;
      if (grow < NN) *(bf16x8*)(&hb[(size_t)grow*64 + c2*8]) = v;
    }
  }

  f32x4 acc2[8] = {};
  // GEMM2 part 1: K = 0..64 -> c = h (A from LDS, B coalesced)
  #pragma unroll
  for (int kb = 0; kb < 64; kb += 32) {
    bf16x8 af = *(const bf16x8*)(&hs[(wv*16 + mloc)*HSP + kb + kg*8]);
    const int kbi = kb >> 5;
    #pragma unroll
    for (int j = 0; j < 8; ++j) {
      bf16x8 bf = *(const bf16x8*)(&W2s[((kbi*8 + j)*64 + lane)*8]);
      acc2[j] = __builtin_amdgcn_mfma_f32_16x16x32_bf16(af, bf, acc2[j], 0,0,0);
    }
  }
  // GEMM2 part 2: K = 64..128 -> c = prev (A scattered, B coalesced)
  #pragma unroll
  for (int kb = 0; kb < 64; kb += 32) {
    bf16x8 af = *(const bf16x8*)(&prevb[(size_t)arow*64 + kb + kg*8]);
    const int kbi = 2 + (kb >> 5);
    #pragma unroll
    for (int j = 0; j < 8; ++j) {
      bf16x8 bf = *(const bf16x8*)(&W2s[((kbi*8 + j)*64 + lane)*8]);
      acc2[j] = __builtin_amdgcn_mfma_f32_16x16x32_bf16(af, bf, acc2[j], 0,0,0);
    }
  }

  // epilogue 2: pr = relu(.+pb), g = sigmoid(.+tb), out = g*pr + (1-g)*h
  #pragma unroll
  for (int j = 0; j < 4; ++j) {
    int col = j*16 + mloc;
    float bp = bias2[col];
    float bt = bias2[64 + col];
    #pragma unroll
    for (int r = 0; r < 4; ++r) {
      float pr = fmaxf(acc2[j][r] + bp, 0.0f);
      float g  = sigmoidf_(acc2[j+4][r] + bt);
      float hv = acc1[j][r];
      float ov = g*pr + (1.0f - g)*hv;
      if (LAYER1) {
        hs[(wv*16 + kg*4 + r)*HSP + col] = (__bf16)ov;   // reuse hs (h consumed)
      } else {
        outs[(wv*16 + kg*4 + r)*64 + col] = ov;          // stage for coalesced store
      }
    }
  }
  if (LAYER1) {
    #pragma unroll
    for (int i = 0; i < 2; ++i) {
      int r2 = i*8 + (lane >> 3);
      int c2 = lane & 7;
      bf16x8 v = *(const bf16x8*)(&hs[(wv*16 + r2)*HSP + c2*8]);
      int grow = wb + r2;
      if (grow < NN) *(bf16x8*)(&gb[(size_t)grow*64 + c2*8]) = v;
    }
  } else {
    #pragma unroll
    for (int i = 0; i < 4; ++i) {
      int pos = i*256 + lane*4;     // 0..1023 over 16 rows x 64 f32
      int r2 = pos >> 6, c2 = pos & 63;
      int grow = wb + r2;
      if (grow < NN)
        *(f32x4*)(&outp[(size_t)grow*64 + c2]) =
            *(const f32x4*)(&outs[(wv*16 + r2)*64 + c2]);
    }
  }
}

extern "C" void kernel_launch(void* const* d_in, const int* in_sizes, int n_in,
                              void* d_out, int out_size, void* d_ws, size_t ws_size,
                              hipStream_t stream){
  const float* x    = (const float*)d_in[0];
  const int*   src  = (const int*)d_in[1];
  const int*   dst  = (const int*)d_in[2];
  const int*   rel  = (const int*)d_in[3];
  const float* c1w  = (const float*)d_in[4];
  const float* c1b  = (const float*)d_in[5];
  const float* c1ws = (const float*)d_in[6];
  const float* c1bs = (const float*)d_in[7];
  const float* h1pw = (const float*)d_in[8];
  const float* h1pb = (const float*)d_in[9];
  const float* h1tw = (const float*)d_in[10];
  const float* h1tb = (const float*)d_in[11];
  const float* c2w  = (const float*)d_in[12];
  const float* c2b  = (const float*)d_in[13];
  const float* c2ws = (const float*)d_in[14];
  const float* c2bs = (const float*)d_in[15];
  const float* h2pw = (const float*)d_in[16];
  const float* h2pb = (const float*)d_in[17];
  const float* h2tw = (const float*)d_in[18];
  const float* h2tb = (const float*)d_in[19];

  char* p = (char*)d_ws;
  __bf16* segb = (__bf16*)p;  p += (size_t)NRR*64*2;
  __bf16* xb   = (__bf16*)p;  p += (size_t)NN*64*2;
  __bf16* h1b  = (__bf16*)p;  p += (size_t)NN*64*2;
  __bf16* g1b  = (__bf16*)p;  p += (size_t)NN*64*2;
  unsigned* ebuck = (unsigned*)p; p += (size_t)NE*4;
  unsigned* ebin  = (unsigned*)p; p += (size_t)NE*4;
  int* soff    = (int*)p;     p += (size_t)(NRR+8)*4;
  int* bincnt  = (int*)p;     p += 128*4;
  int* binoff  = (int*)p;     p += 128*4;
  int* bincur  = (int*)p;     p += 128*4;
  __bf16* W1a  = (__bf16*)p;  p += 64*320*2;
  __bf16* W2a  = (__bf16*)p;  p += 128*128*2;
  __bf16* W1b  = (__bf16*)p;  p += 64*320*2;
  __bf16* W2b  = (__bf16*)p;  p += 128*128*2;
  float* B1a   = (float*)p;   p += 64*4;
  float* B2a   = (float*)p;   p += 128*4;
  float* B1b   = (float*)p;   p += 64*4;
  float* B2b   = (float*)p;   p += 128*4;

  float* out = (float*)d_out;

  // segment-level counting sort of edges (shared by both layers)
  hipMemsetAsync(bincnt, 0, 128*4, stream);
  binhist_kernel<<<512, 256, 0, stream>>>(dst, rel, bincnt);
  binscan_kernel<<<1, 64, 0, stream>>>(bincnt, binoff, bincur, soff);
  passA_kernel<<<(NE+EPB-1)/EPB, 256, 0, stream>>>(src, dst, rel, bincur, ebin);
  passB_kernel<<<NBIN, 1024, 0, stream>>>(ebin, binoff, soff, ebuck);

  tobf16_kernel<<<(NN*64/8 + 255)/256, 256, 0, stream>>>(x, xb);
  prep_kernel<<<80, 256, 0, stream>>>(c1w, c1b, c1ws, c1bs, h1pw, h1pb, h1tw, h1tb,
                                      c2w, c2b, c2ws, c2bs, h2pw, h2pb, h2tw, h2tb,
                                      W1a, W2a, B1a, B2a, W1b, W2b, B1b, B2b);

  // layer 1
  gather_kernel<<<NRR/32, 256, 0, stream>>>(ebuck, soff, xb, segb);
  dense_kernel<true><<<(NN+63)/64, 256, 0, stream>>>(segb, xb, xb, W1a, W2a, B1a, B2a,
                                                     h1b, g1b, nullptr);
  // layer 2
  gather_kernel<<<NRR/32, 256, 0, stream>>>(ebuck, soff, g1b, segb);
  dense_kernel<false><<<(NN+63)/64, 256, 0, stream>>>(segb, g1b, h1b, W1b, W2b, B1b, B2b,
                                                      nullptr, nullptr, out);
}